// Round 13
// baseline (242.751 us; speedup 1.0000x reference)
//
#include <hip/hip_runtime.h>

// GCN: x1 = relu(Agg(x@W1)+b1); x2 = relu(Agg(x1@W2)+b2); out = [x1,x2]@linW + linb
// Agg via CSR (counting sort) + per-node wave gather-reduce; h stored bf16.
// GEMMs via MFMA bf16x3 fp32-emulation (hi*hi + lo*hi + hi*lo), R10-verified.
// R13: latency-bound kernels get more MLP: agg 16 edges in flight (was 8),
// fill 2 edges/thread, count 4 edges/thread (int4).

#define D128 128

typedef __attribute__((ext_vector_type(8))) short bf16x8;
typedef __attribute__((ext_vector_type(4))) float f32x4;

__device__ __forceinline__ unsigned short f2bf_bits(float v) {
    unsigned int u = __float_as_uint(v);
    unsigned int r = u + 0x7FFFu + ((u >> 16) & 1u);   // RNE
    return (unsigned short)(r >> 16);
}
__device__ __forceinline__ float bf2f(unsigned short h) {
    return __uint_as_float(((unsigned int)h) << 16);
}
__device__ __forceinline__ void mfma3(f32x4& acc, bf16x8 ah, bf16x8 al,
                                      bf16x8 wh, bf16x8 wl) {
    acc = __builtin_amdgcn_mfma_f32_16x16x32_bf16(ah, wh, acc, 0, 0, 0);
    acc = __builtin_amdgcn_mfma_f32_16x16x32_bf16(al, wh, acc, 0, 0, 0);
    acc = __builtin_amdgcn_mfma_f32_16x16x32_bf16(ah, wl, acc, 0, 0, 0);
}

// ---------- degree count: 4 edges/thread ----------
__global__ void k_count(const int* __restrict__ dst, int* __restrict__ indeg, int E) {
    int base = (blockIdx.x * 256 + threadIdx.x) * 4;
    if (base + 3 < E) {
        int4 d = *(const int4*)&dst[base];
        atomicAdd(&indeg[d.x], 1);
        atomicAdd(&indeg[d.y], 1);
        atomicAdd(&indeg[d.z], 1);
        atomicAdd(&indeg[d.w], 1);
    } else {
        for (int e = base; e < E; ++e) atomicAdd(&indeg[dst[e]], 1);
    }
}

// ---------- scan (exclusive) over indeg -> row_ptr ; fused dinv ----------
__global__ void k_scan1(const int* __restrict__ indeg, int* __restrict__ row_ptr,
                        int* __restrict__ bsum, float* __restrict__ dinv, int n) {
    __shared__ int tmp[256];
    int i = blockIdx.x * 256 + threadIdx.x;
    int v = (i < n) ? indeg[i] : 0;
    if (i < n) dinv[i] = rsqrtf((float)(v + 1));  // +1 self loop
    tmp[threadIdx.x] = v;
    __syncthreads();
    for (int off = 1; off < 256; off <<= 1) {
        int t = (threadIdx.x >= off) ? tmp[threadIdx.x - off] : 0;
        __syncthreads();
        tmp[threadIdx.x] += t;
        __syncthreads();
    }
    if (i < n) row_ptr[i] = tmp[threadIdx.x] - v;
    if (threadIdx.x == 255) bsum[blockIdx.x] = tmp[255];
}

__global__ void k_scan2(int* __restrict__ bsum, int nb) {  // one block, nb<=256
    __shared__ int tmp[256];
    int v = (threadIdx.x < nb) ? bsum[threadIdx.x] : 0;
    tmp[threadIdx.x] = v;
    __syncthreads();
    for (int off = 1; off < 256; off <<= 1) {
        int t = (threadIdx.x >= off) ? tmp[threadIdx.x - off] : 0;
        __syncthreads();
        tmp[threadIdx.x] += t;
        __syncthreads();
    }
    if (threadIdx.x < nb) bsum[threadIdx.x] = tmp[threadIdx.x] - v;
}

__global__ void k_scan3(int* __restrict__ row_ptr, const int* __restrict__ bsum,
                        int* __restrict__ cursor, int n, int E) {
    int i = blockIdx.x * 256 + threadIdx.x;
    if (i < n) {
        int r = row_ptr[i] + bsum[blockIdx.x];
        row_ptr[i] = r;
        cursor[i] = r;
    }
    if (blockIdx.x == 0 && threadIdx.x == 0) row_ptr[n] = E;
}

// ---------- fused aggregate + bias + relu ; h is packed bf16x2 ----------
// 1 wave per node; 16 edges in flight.
__global__ __launch_bounds__(256) void k_agg_csr(
    const unsigned int* __restrict__ h, const int* __restrict__ row_ptr,
    const float2* __restrict__ csr, const float* __restrict__ dinv,
    const float* __restrict__ bias, float* __restrict__ o, int n)
{
    int node = blockIdx.x * 4 + (threadIdx.x >> 6);
    int lane = threadIdx.x & 63;
    if (node >= n) return;
    float dv = dinv[node];
    unsigned int su = h[node * 64 + lane];
    float ax = dv * dv * __uint_as_float(su << 16);
    float ay = dv * dv * __uint_as_float(su & 0xFFFF0000u);
    int j = row_ptr[node], end = row_ptr[node + 1];
    for (; j + 15 < end; j += 16) {
        float2 c[16];
        unsigned int u[16];
#pragma unroll
        for (int i = 0; i < 16; ++i) c[i] = csr[j + i];
#pragma unroll
        for (int i = 0; i < 16; ++i) u[i] = h[__float_as_int(c[i].x) * 64 + lane];
#pragma unroll
        for (int i = 0; i < 16; ++i) {
            ax += c[i].y * __uint_as_float(u[i] << 16);
            ay += c[i].y * __uint_as_float(u[i] & 0xFFFF0000u);
        }
    }
    for (; j + 7 < end; j += 8) {
        float2 c[8];
        unsigned int u[8];
#pragma unroll
        for (int i = 0; i < 8; ++i) c[i] = csr[j + i];
#pragma unroll
        for (int i = 0; i < 8; ++i) u[i] = h[__float_as_int(c[i].x) * 64 + lane];
#pragma unroll
        for (int i = 0; i < 8; ++i) {
            ax += c[i].y * __uint_as_float(u[i] << 16);
            ay += c[i].y * __uint_as_float(u[i] & 0xFFFF0000u);
        }
    }
    for (; j < end; ++j) {
        float2 c = csr[j];
        unsigned int u = h[__float_as_int(c.x) * 64 + lane];
        ax += c.y * __uint_as_float(u << 16);
        ay += c.y * __uint_as_float(u & 0xFFFF0000u);
    }
    float2 bv = ((const float2*)bias)[lane];
    float2 ov = {fmaxf(ax + bv.x, 0.f), fmaxf(ay + bv.y, 0.f)};
    ((float2*)o)[node * 64 + lane] = ov;
}

// ---------- MFMA GEMM building blocks (R10-verified layouts) ----------
__device__ __forceinline__ void stage_A_tile(
    const float* __restrict__ A, int brow, int n, int tid,
    unsigned short* __restrict__ Ah, unsigned short* __restrict__ Al)
{
    const float4* A4 = (const float4*)(A + (size_t)brow * D128);
#pragma unroll
    for (int it = 0; it < 8; ++it) {
        int f = it * 256 + tid;
        int r = f >> 5, k4 = f & 31;
        float4 v = make_float4(0.f, 0.f, 0.f, 0.f);
        if (brow + r < n) v = A4[f];
        int lane_ = (r & 15) + 16 * ((k4 >> 1) & 3);
        int base = ((((k4 >> 3) * 4 + (r >> 4)) * 64 + lane_) << 3) + (k4 & 1) * 4;
        float vv[4] = {v.x, v.y, v.z, v.w};
        ushort4 hh, ll;
        unsigned short* hp = (unsigned short*)&hh;
        unsigned short* lp = (unsigned short*)&ll;
#pragma unroll
        for (int q = 0; q < 4; ++q) {
            unsigned short hb = f2bf_bits(vv[q]);
            hp[q] = hb;
            lp[q] = f2bf_bits(vv[q] - bf2f(hb));
        }
        *(ushort4*)&Ah[base] = hh;
        *(ushort4*)&Al[base] = ll;
    }
}

__device__ __forceinline__ void load_W_s(
    const float* __restrict__ W, int s, int colbase, int lanen, int kb,
    bf16x8 wh[2], bf16x8 wl[2])
{
#pragma unroll
    for (int t = 0; t < 2; ++t)
#pragma unroll
        for (int j = 0; j < 8; ++j) {
            float v = W[(size_t)(s * 32 + kb + j) * D128 + colbase + t * 16 + lanen];
            unsigned short hb = f2bf_bits(v);
            wh[t][j] = (short)hb;
            wl[t][j] = (short)f2bf_bits(v - bf2f(hb));
        }
}

__device__ __forceinline__ void epilogue(
    f32x4 acc[4][2], float* __restrict__ C, const float* __restrict__ bias,
    int brow, int n, int colbase, int lanen, int l, int out_bf, int addC)
{
    float bv[2] = {0.f, 0.f};
    if (bias) { bv[0] = bias[colbase + lanen]; bv[1] = bias[colbase + 16 + lanen]; }
    int rsub = (l >> 4) * 4;
    if (out_bf) {
        unsigned short* Cb = (unsigned short*)C;
#pragma unroll
        for (int m = 0; m < 4; ++m)
#pragma unroll
            for (int t = 0; t < 2; ++t)
#pragma unroll
                for (int r = 0; r < 4; ++r) {
                    int row = brow + m * 16 + rsub + r;
                    if (row < n)
                        Cb[(size_t)row * D128 + colbase + t * 16 + lanen] = f2bf_bits(acc[m][t][r]);
                }
    } else {
#pragma unroll
        for (int m = 0; m < 4; ++m)
#pragma unroll
            for (int t = 0; t < 2; ++t)
#pragma unroll
                for (int r = 0; r < 4; ++r) {
                    int row = brow + m * 16 + rsub + r;
                    if (row < n) {
                        size_t idx = (size_t)row * D128 + colbase + t * 16 + lanen;
                        float v = acc[m][t][r] + bv[t];
                        if (addC) v += C[idx];
                        C[idx] = v;
                    }
                }
    }
}

__device__ __forceinline__ void gemm_core(
    const float* __restrict__ A, const float* __restrict__ W,
    const float* __restrict__ bias, float* __restrict__ C,
    int n, int out_bf, int addC, int bid, int tid,
    unsigned short* __restrict__ Ah, unsigned short* __restrict__ Al)
{
    int l = tid & 63;
    int wv = tid >> 6;
    int brow = bid * 64;
    int colbase = wv * 32;
    int lanen = l & 15;
    int kb = (l >> 4) * 8;

    f32x4 acc[4][2];
#pragma unroll
    for (int m = 0; m < 4; ++m)
#pragma unroll
        for (int t = 0; t < 2; ++t) acc[m][t] = (f32x4){0.f, 0.f, 0.f, 0.f};

    stage_A_tile(A, brow, n, tid, Ah, Al);
    __syncthreads();

#pragma unroll
    for (int s = 0; s < 4; ++s) {
        bf16x8 wh[2], wl[2];
        load_W_s(W, s, colbase, lanen, kb, wh, wl);
#pragma unroll
        for (int m = 0; m < 4; ++m) {
            int fb = ((s * 4 + m) * 64 + l) * 8;
            bf16x8 ah = *(const bf16x8*)&Ah[fb];
            bf16x8 al = *(const bf16x8*)&Al[fb];
#pragma unroll
            for (int t = 0; t < 2; ++t) mfma3(acc[m][t], ah, al, wh[t], wl[t]);
        }
    }
    epilogue(acc, C, bias, brow, n, colbase, lanen, l, out_bf, addC);
}

// ---------- fused: gemm1 (blocks < gemmBlocks) + CSR fill (2 edges/thread) ----------
__global__ __launch_bounds__(256, 2) void k_gemm1_fill(
    const float* __restrict__ x, const float* __restrict__ W1,
    float* __restrict__ h, int n,
    const int* __restrict__ src, const int* __restrict__ dst,
    const float* __restrict__ dinv, int* __restrict__ cursor,
    float2* __restrict__ csr, int E, int gemmBlocks)
{
    __shared__ unsigned short Ah[4 * 4 * 64 * 8];
    __shared__ unsigned short Al[4 * 4 * 64 * 8];
    if (blockIdx.x < gemmBlocks) {
        gemm_core(x, W1, nullptr, h, n, 1, 0, blockIdx.x, threadIdx.x, Ah, Al);
    } else {
        int e0 = (blockIdx.x - gemmBlocks) * 512 + threadIdx.x;
        int e1 = e0 + 256;
        int s0 = 0, d0 = 0, s1 = 0, d1 = 0;
        bool v0 = e0 < E, v1 = e1 < E;
        if (v0) { s0 = src[e0]; d0 = dst[e0]; }
        if (v1) { s1 = src[e1]; d1 = dst[e1]; }
        if (v0) {
            float nm = dinv[s0] * dinv[d0];
            int pos = atomicAdd(&cursor[d0], 1);
            csr[pos] = make_float2(__int_as_float(s0), nm);
        }
        if (v1) {
            float nm = dinv[s1] * dinv[d1];
            int pos = atomicAdd(&cursor[d1], 1);
            csr[pos] = make_float2(__int_as_float(s1), nm);
        }
    }
}

// ---------- standalone single-source gemm (gemm3b) ----------
__global__ __launch_bounds__(256, 2) void k_gemm_mfma(
    const float* __restrict__ A, const float* __restrict__ W,
    const float* __restrict__ bias, float* __restrict__ C,
    int n, int out_bf, int addC)
{
    __shared__ unsigned short Ah[4 * 4 * 64 * 8];
    __shared__ unsigned short Al[4 * 4 * 64 * 8];
    gemm_core(A, W, bias, C, n, out_bf, addC, blockIdx.x, threadIdx.x, Ah, Al);
}

// ---------- dual: h2 = bf16(x1@W2), p = x1@linW_top (one A staging) ----------
__global__ __launch_bounds__(256, 2) void k_gemm_dual(
    const float* __restrict__ A, const float* __restrict__ W2,
    const float* __restrict__ Wtop, float* __restrict__ hOut,
    float* __restrict__ pOut, int n)
{
    __shared__ unsigned short Ah[4 * 4 * 64 * 8];
    __shared__ unsigned short Al[4 * 4 * 64 * 8];
    int tid = threadIdx.x;
    int l = tid & 63;
    int wv = tid >> 6;
    int brow = blockIdx.x * 64;
    int colbase = wv * 32;
    int lanen = l & 15;
    int kb = (l >> 4) * 8;

    f32x4 accA[4][2], accB[4][2];
#pragma unroll
    for (int m = 0; m < 4; ++m)
#pragma unroll
        for (int t = 0; t < 2; ++t) {
            accA[m][t] = (f32x4){0.f, 0.f, 0.f, 0.f};
            accB[m][t] = (f32x4){0.f, 0.f, 0.f, 0.f};
        }

    stage_A_tile(A, brow, n, tid, Ah, Al);
    __syncthreads();

#pragma unroll
    for (int s = 0; s < 4; ++s) {
        bf16x8 whA[2], wlA[2], whB[2], wlB[2];
        load_W_s(W2, s, colbase, lanen, kb, whA, wlA);
        load_W_s(Wtop, s, colbase, lanen, kb, whB, wlB);
#pragma unroll
        for (int m = 0; m < 4; ++m) {
            int fb = ((s * 4 + m) * 64 + l) * 8;
            bf16x8 ah = *(const bf16x8*)&Ah[fb];
            bf16x8 al = *(const bf16x8*)&Al[fb];
#pragma unroll
            for (int t = 0; t < 2; ++t) {
                mfma3(accA[m][t], ah, al, whA[t], wlA[t]);
                mfma3(accB[m][t], ah, al, whB[t], wlB[t]);
            }
        }
    }
    epilogue(accA, hOut, nullptr, brow, n, colbase, lanen, l, 1, 0);
    epilogue(accB, pOut, nullptr, brow, n, colbase, lanen, l, 0, 0);
}

extern "C" void kernel_launch(void* const* d_in, const int* in_sizes, int n_in,
                              void* d_out, int out_size, void* d_ws, size_t ws_size,
                              hipStream_t stream) {
    const float* x    = (const float*)d_in[0];
    const int*   ei   = (const int*)d_in[1];
    const float* W1   = (const float*)d_in[2];
    const float* b1   = (const float*)d_in[3];
    const float* W2   = (const float*)d_in[4];
    const float* b2   = (const float*)d_in[5];
    const float* linW = (const float*)d_in[6];
    const float* linb = (const float*)d_in[7];

    int n = in_sizes[0] / D128;
    int E = in_sizes[1] / 2;
    const int* src = ei;
    const int* dst = ei + E;

    float* out = (float*)d_out;
    float* ws  = (float*)d_ws;

    // ws (floats): csr[2E] | indeg[n] | dinv[n] | row_ptr[n+1] | bsum[256]
    //              | cursor[n] | align | x1[n*128] | x2[n*128] | h[n*64 uints]
    size_t o = 0;
    float2* csr   = (float2*)(ws + o);  o += 2 * (size_t)E;
    int*   indeg  = (int*)(ws + o);     o += n;
    float* dinv   = ws + o;             o += n;
    int*   row_ptr= (int*)(ws + o);     o += n + 1;
    int*   bsum   = (int*)(ws + o);     o += 256;
    int*   cursor = (int*)(ws + o);     o += n;
    o = (o + 3) & ~(size_t)3;
    float* x1     = ws + o;             o += (size_t)n * D128;
    float* x2     = ws + o;             o += (size_t)n * D128;
    float* h      = ws + o;             // bf16-packed, n*64 uints

    int gn = (n + 255) / 256;
    int gE4 = (E + 1023) / 1024;        // 4 edges/thread
    int gFill = (E + 511) / 512;        // 2 edges/thread
    int gemmBlocks = (n + 63) / 64;
    int aggBlocks  = (n + 3) / 4;

    // CSR prep
    (void)hipMemsetAsync(indeg, 0, (size_t)n * sizeof(int), stream);
    k_count<<<gE4, 256, 0, stream>>>(dst, indeg, E);
    k_scan1<<<gn, 256, 0, stream>>>(indeg, row_ptr, bsum, dinv, n);
    k_scan2<<<1, 256, 0, stream>>>(bsum, gn);
    k_scan3<<<gn, 256, 0, stream>>>(row_ptr, bsum, cursor, n, E);

    // gemm1 (h = bf16(x@W1)) fused with CSR fill
    k_gemm1_fill<<<gemmBlocks + gFill, 256, 0, stream>>>(
        x, W1, h, n, src, dst, dinv, cursor, csr, E, gemmBlocks);

    // layer 1 aggregate
    k_agg_csr<<<aggBlocks, 256, 0, stream>>>((const unsigned int*)h, row_ptr, csr, dinv, b1, x1, n);

    // layer 2 gemm + first half of final linear (shared A staging)
    k_gemm_dual<<<gemmBlocks, 256, 0, stream>>>(x1, W2, linW, h, out, n);

    // layer 2 aggregate
    k_agg_csr<<<aggBlocks, 256, 0, stream>>>((const unsigned int*)h, row_ptr, csr, dinv, b2, x2, n);

    // final: out += x2 @ linW[128:256] + linb
    k_gemm_mfma<<<gemmBlocks, 256, 0, stream>>>(x2, linW + 128 * D128, linb, out, n, 0, 1);
}

// Round 14
// 235.254 us; speedup vs baseline: 1.0319x; 1.0319x over previous
//
#include <hip/hip_runtime.h>

// GCN: x1 = relu(Agg(x@W1)+b1); x2 = relu(Agg(x1@W2)+b2); out = [x1,x2]@linW + linb
// Agg via CSR (counting sort) + per-node wave gather-reduce; h stored bf16.
// GEMMs via MFMA bf16x3 fp32-emulation (hi*hi + lo*hi + hi*lo), R10-verified.
// R14 = R12 base + agg processes 2 edges per wave instruction (lane halves,
// uint2/lane = 4 bf16 channels): 8 loads/lane cover 16 edges -> 2x MLP per
// instruction without the R13 register-rolling failure.

#define D128 128

typedef __attribute__((ext_vector_type(8))) short bf16x8;
typedef __attribute__((ext_vector_type(4))) float f32x4;

__device__ __forceinline__ unsigned short f2bf_bits(float v) {
    unsigned int u = __float_as_uint(v);
    unsigned int r = u + 0x7FFFu + ((u >> 16) & 1u);   // RNE
    return (unsigned short)(r >> 16);
}
__device__ __forceinline__ float bf2f(unsigned short h) {
    return __uint_as_float(((unsigned int)h) << 16);
}
__device__ __forceinline__ float bflo(unsigned int u) { return __uint_as_float(u << 16); }
__device__ __forceinline__ float bfhi(unsigned int u) { return __uint_as_float(u & 0xFFFF0000u); }

__device__ __forceinline__ void mfma3(f32x4& acc, bf16x8 ah, bf16x8 al,
                                      bf16x8 wh, bf16x8 wl) {
    acc = __builtin_amdgcn_mfma_f32_16x16x32_bf16(ah, wh, acc, 0, 0, 0);
    acc = __builtin_amdgcn_mfma_f32_16x16x32_bf16(al, wh, acc, 0, 0, 0);
    acc = __builtin_amdgcn_mfma_f32_16x16x32_bf16(ah, wl, acc, 0, 0, 0);
}

// ---------- degree count: 4 edges/thread ----------
__global__ void k_count(const int* __restrict__ dst, int* __restrict__ indeg, int E) {
    int base = (blockIdx.x * 256 + threadIdx.x) * 4;
    if (base + 3 < E) {
        int4 d = *(const int4*)&dst[base];
        atomicAdd(&indeg[d.x], 1);
        atomicAdd(&indeg[d.y], 1);
        atomicAdd(&indeg[d.z], 1);
        atomicAdd(&indeg[d.w], 1);
    } else {
        for (int e = base; e < E; ++e) atomicAdd(&indeg[dst[e]], 1);
    }
}

// ---------- scan (exclusive) over indeg -> row_ptr ; fused dinv ----------
__global__ void k_scan1(const int* __restrict__ indeg, int* __restrict__ row_ptr,
                        int* __restrict__ bsum, float* __restrict__ dinv, int n) {
    __shared__ int tmp[256];
    int i = blockIdx.x * 256 + threadIdx.x;
    int v = (i < n) ? indeg[i] : 0;
    if (i < n) dinv[i] = rsqrtf((float)(v + 1));  // +1 self loop
    tmp[threadIdx.x] = v;
    __syncthreads();
    for (int off = 1; off < 256; off <<= 1) {
        int t = (threadIdx.x >= off) ? tmp[threadIdx.x - off] : 0;
        __syncthreads();
        tmp[threadIdx.x] += t;
        __syncthreads();
    }
    if (i < n) row_ptr[i] = tmp[threadIdx.x] - v;
    if (threadIdx.x == 255) bsum[blockIdx.x] = tmp[255];
}

__global__ void k_scan2(int* __restrict__ bsum, int nb) {  // one block, nb<=256
    __shared__ int tmp[256];
    int v = (threadIdx.x < nb) ? bsum[threadIdx.x] : 0;
    tmp[threadIdx.x] = v;
    __syncthreads();
    for (int off = 1; off < 256; off <<= 1) {
        int t = (threadIdx.x >= off) ? tmp[threadIdx.x - off] : 0;
        __syncthreads();
        tmp[threadIdx.x] += t;
        __syncthreads();
    }
    if (threadIdx.x < nb) bsum[threadIdx.x] = tmp[threadIdx.x] - v;
}

__global__ void k_scan3(int* __restrict__ row_ptr, const int* __restrict__ bsum,
                        int* __restrict__ cursor, int n, int E) {
    int i = blockIdx.x * 256 + threadIdx.x;
    if (i < n) {
        int r = row_ptr[i] + bsum[blockIdx.x];
        row_ptr[i] = r;
        cursor[i] = r;
    }
    if (blockIdx.x == 0 && threadIdx.x == 0) row_ptr[n] = E;
}

// ---------- fused aggregate + bias + relu ; h is packed bf16x2 ----------
// 1 wave per node; lane halves process 2 edges per instruction, uint2/lane.
__global__ __launch_bounds__(256) void k_agg_csr(
    const unsigned int* __restrict__ h, const int* __restrict__ row_ptr,
    const float2* __restrict__ csr, const float* __restrict__ dinv,
    const float* __restrict__ bias, float* __restrict__ o, int n)
{
    int node = blockIdx.x * 4 + (threadIdx.x >> 6);
    int lane = threadIdx.x & 63;
    if (node >= n) return;
    int half = lane >> 5;           // which edge of the pair
    int cl = lane & 31;             // channel quad: ch 4cl..4cl+3
    const uint2* h2 = (const uint2*)h;

    float ax = 0.f, ay = 0.f, az = 0.f, aw = 0.f;
    if (half == 0) {                // self-loop term counted once
        float dv = dinv[node];
        float s2 = dv * dv;
        uint2 su = h2[(size_t)node * 32 + cl];
        ax = s2 * bflo(su.x); ay = s2 * bfhi(su.x);
        az = s2 * bflo(su.y); aw = s2 * bfhi(su.y);
    }

    int j = row_ptr[node], end = row_ptr[node + 1];
    for (; j + 15 < end; j += 16) {       // 8 pairs fully valid
        float2 c[8]; uint2 u[8];
#pragma unroll
        for (int i = 0; i < 8; ++i) c[i] = csr[j + 2 * i + half];
#pragma unroll
        for (int i = 0; i < 8; ++i) u[i] = h2[(size_t)__float_as_int(c[i].x) * 32 + cl];
#pragma unroll
        for (int i = 0; i < 8; ++i) {
            float nm = c[i].y;
            ax += nm * bflo(u[i].x); ay += nm * bfhi(u[i].x);
            az += nm * bflo(u[i].y); aw += nm * bfhi(u[i].y);
        }
    }
    for (; j + 7 < end; j += 8) {         // 4 pairs fully valid
        float2 c[4]; uint2 u[4];
#pragma unroll
        for (int i = 0; i < 4; ++i) c[i] = csr[j + 2 * i + half];
#pragma unroll
        for (int i = 0; i < 4; ++i) u[i] = h2[(size_t)__float_as_int(c[i].x) * 32 + cl];
#pragma unroll
        for (int i = 0; i < 4; ++i) {
            float nm = c[i].y;
            ax += nm * bflo(u[i].x); ay += nm * bfhi(u[i].x);
            az += nm * bflo(u[i].y); aw += nm * bfhi(u[i].y);
        }
    }
    for (; j < end; j += 2) {             // masked pair tail
        int e = j + half;
        int ee = (e < end) ? e : (end - 1);
        float2 c = csr[ee];
        uint2 u = h2[(size_t)__float_as_int(c.x) * 32 + cl];
        float nm = (e < end) ? c.y : 0.f;
        ax += nm * bflo(u.x); ay += nm * bfhi(u.x);
        az += nm * bflo(u.y); aw += nm * bfhi(u.y);
    }

    // combine the two edge-stream halves (lane <-> lane+32)
    ax += __shfl_xor(ax, 32);
    ay += __shfl_xor(ay, 32);
    az += __shfl_xor(az, 32);
    aw += __shfl_xor(aw, 32);

    if (half == 0) {
        float4 bv = ((const float4*)bias)[cl];
        float4 ov = {fmaxf(ax + bv.x, 0.f), fmaxf(ay + bv.y, 0.f),
                     fmaxf(az + bv.z, 0.f), fmaxf(aw + bv.w, 0.f)};
        ((float4*)o)[(size_t)node * 32 + cl] = ov;
    }
}

// ---------- MFMA GEMM building blocks (R10-verified layouts) ----------
__device__ __forceinline__ void stage_A_tile(
    const float* __restrict__ A, int brow, int n, int tid,
    unsigned short* __restrict__ Ah, unsigned short* __restrict__ Al)
{
    const float4* A4 = (const float4*)(A + (size_t)brow * D128);
#pragma unroll
    for (int it = 0; it < 8; ++it) {
        int f = it * 256 + tid;
        int r = f >> 5, k4 = f & 31;
        float4 v = make_float4(0.f, 0.f, 0.f, 0.f);
        if (brow + r < n) v = A4[f];
        int lane_ = (r & 15) + 16 * ((k4 >> 1) & 3);
        int base = ((((k4 >> 3) * 4 + (r >> 4)) * 64 + lane_) << 3) + (k4 & 1) * 4;
        float vv[4] = {v.x, v.y, v.z, v.w};
        ushort4 hh, ll;
        unsigned short* hp = (unsigned short*)&hh;
        unsigned short* lp = (unsigned short*)&ll;
#pragma unroll
        for (int q = 0; q < 4; ++q) {
            unsigned short hb = f2bf_bits(vv[q]);
            hp[q] = hb;
            lp[q] = f2bf_bits(vv[q] - bf2f(hb));
        }
        *(ushort4*)&Ah[base] = hh;
        *(ushort4*)&Al[base] = ll;
    }
}

__device__ __forceinline__ void load_W_s(
    const float* __restrict__ W, int s, int colbase, int lanen, int kb,
    bf16x8 wh[2], bf16x8 wl[2])
{
#pragma unroll
    for (int t = 0; t < 2; ++t)
#pragma unroll
        for (int j = 0; j < 8; ++j) {
            float v = W[(size_t)(s * 32 + kb + j) * D128 + colbase + t * 16 + lanen];
            unsigned short hb = f2bf_bits(v);
            wh[t][j] = (short)hb;
            wl[t][j] = (short)f2bf_bits(v - bf2f(hb));
        }
}

__device__ __forceinline__ void epilogue(
    f32x4 acc[4][2], float* __restrict__ C, const float* __restrict__ bias,
    int brow, int n, int colbase, int lanen, int l, int out_bf, int addC)
{
    float bv[2] = {0.f, 0.f};
    if (bias) { bv[0] = bias[colbase + lanen]; bv[1] = bias[colbase + 16 + lanen]; }
    int rsub = (l >> 4) * 4;
    if (out_bf) {
        unsigned short* Cb = (unsigned short*)C;
#pragma unroll
        for (int m = 0; m < 4; ++m)
#pragma unroll
            for (int t = 0; t < 2; ++t)
#pragma unroll
                for (int r = 0; r < 4; ++r) {
                    int row = brow + m * 16 + rsub + r;
                    if (row < n)
                        Cb[(size_t)row * D128 + colbase + t * 16 + lanen] = f2bf_bits(acc[m][t][r]);
                }
    } else {
#pragma unroll
        for (int m = 0; m < 4; ++m)
#pragma unroll
            for (int t = 0; t < 2; ++t)
#pragma unroll
                for (int r = 0; r < 4; ++r) {
                    int row = brow + m * 16 + rsub + r;
                    if (row < n) {
                        size_t idx = (size_t)row * D128 + colbase + t * 16 + lanen;
                        float v = acc[m][t][r] + bv[t];
                        if (addC) v += C[idx];
                        C[idx] = v;
                    }
                }
    }
}

__device__ __forceinline__ void gemm_core(
    const float* __restrict__ A, const float* __restrict__ W,
    const float* __restrict__ bias, float* __restrict__ C,
    int n, int out_bf, int addC, int bid, int tid,
    unsigned short* __restrict__ Ah, unsigned short* __restrict__ Al)
{
    int l = tid & 63;
    int wv = tid >> 6;
    int brow = bid * 64;
    int colbase = wv * 32;
    int lanen = l & 15;
    int kb = (l >> 4) * 8;

    f32x4 acc[4][2];
#pragma unroll
    for (int m = 0; m < 4; ++m)
#pragma unroll
        for (int t = 0; t < 2; ++t) acc[m][t] = (f32x4){0.f, 0.f, 0.f, 0.f};

    stage_A_tile(A, brow, n, tid, Ah, Al);
    __syncthreads();

#pragma unroll
    for (int s = 0; s < 4; ++s) {
        bf16x8 wh[2], wl[2];
        load_W_s(W, s, colbase, lanen, kb, wh, wl);
#pragma unroll
        for (int m = 0; m < 4; ++m) {
            int fb = ((s * 4 + m) * 64 + l) * 8;
            bf16x8 ah = *(const bf16x8*)&Ah[fb];
            bf16x8 al = *(const bf16x8*)&Al[fb];
#pragma unroll
            for (int t = 0; t < 2; ++t) mfma3(acc[m][t], ah, al, wh[t], wl[t]);
        }
    }
    epilogue(acc, C, bias, brow, n, colbase, lanen, l, out_bf, addC);
}

// ---------- fused: gemm1 (blocks < gemmBlocks) + CSR fill (rest) ----------
__global__ __launch_bounds__(256, 2) void k_gemm1_fill(
    const float* __restrict__ x, const float* __restrict__ W1,
    float* __restrict__ h, int n,
    const int* __restrict__ src, const int* __restrict__ dst,
    const float* __restrict__ dinv, int* __restrict__ cursor,
    float2* __restrict__ csr, int E, int gemmBlocks)
{
    __shared__ unsigned short Ah[4 * 4 * 64 * 8];
    __shared__ unsigned short Al[4 * 4 * 64 * 8];
    if (blockIdx.x < gemmBlocks) {
        gemm_core(x, W1, nullptr, h, n, 1, 0, blockIdx.x, threadIdx.x, Ah, Al);
    } else {
        int e = (blockIdx.x - gemmBlocks) * 256 + threadIdx.x;
        if (e >= E) return;
        int s = src[e], d = dst[e];
        int pos = atomicAdd(&cursor[d], 1);
        csr[pos] = make_float2(__int_as_float(s), dinv[s] * dinv[d]);
    }
}

// ---------- standalone single-source gemm (gemm3b) ----------
__global__ __launch_bounds__(256, 2) void k_gemm_mfma(
    const float* __restrict__ A, const float* __restrict__ W,
    const float* __restrict__ bias, float* __restrict__ C,
    int n, int out_bf, int addC)
{
    __shared__ unsigned short Ah[4 * 4 * 64 * 8];
    __shared__ unsigned short Al[4 * 4 * 64 * 8];
    gemm_core(A, W, bias, C, n, out_bf, addC, blockIdx.x, threadIdx.x, Ah, Al);
}

// ---------- dual: h2 = bf16(x1@W2), p = x1@linW_top (one A staging) ----------
__global__ __launch_bounds__(256, 2) void k_gemm_dual(
    const float* __restrict__ A, const float* __restrict__ W2,
    const float* __restrict__ Wtop, float* __restrict__ hOut,
    float* __restrict__ pOut, int n)
{
    __shared__ unsigned short Ah[4 * 4 * 64 * 8];
    __shared__ unsigned short Al[4 * 4 * 64 * 8];
    int tid = threadIdx.x;
    int l = tid & 63;
    int wv = tid >> 6;
    int brow = blockIdx.x * 64;
    int colbase = wv * 32;
    int lanen = l & 15;
    int kb = (l >> 4) * 8;

    f32x4 accA[4][2], accB[4][2];
#pragma unroll
    for (int m = 0; m < 4; ++m)
#pragma unroll
        for (int t = 0; t < 2; ++t) {
            accA[m][t] = (f32x4){0.f, 0.f, 0.f, 0.f};
            accB[m][t] = (f32x4){0.f, 0.f, 0.f, 0.f};
        }

    stage_A_tile(A, brow, n, tid, Ah, Al);
    __syncthreads();

#pragma unroll
    for (int s = 0; s < 4; ++s) {
        bf16x8 whA[2], wlA[2], whB[2], wlB[2];
        load_W_s(W2, s, colbase, lanen, kb, whA, wlA);
        load_W_s(Wtop, s, colbase, lanen, kb, whB, wlB);
#pragma unroll
        for (int m = 0; m < 4; ++m) {
            int fb = ((s * 4 + m) * 64 + l) * 8;
            bf16x8 ah = *(const bf16x8*)&Ah[fb];
            bf16x8 al = *(const bf16x8*)&Al[fb];
#pragma unroll
            for (int t = 0; t < 2; ++t) {
                mfma3(accA[m][t], ah, al, whA[t], wlA[t]);
                mfma3(accB[m][t], ah, al, whB[t], wlB[t]);
            }
        }
    }
    epilogue(accA, hOut, nullptr, brow, n, colbase, lanen, l, 1, 0);
    epilogue(accB, pOut, nullptr, brow, n, colbase, lanen, l, 0, 0);
}

extern "C" void kernel_launch(void* const* d_in, const int* in_sizes, int n_in,
                              void* d_out, int out_size, void* d_ws, size_t ws_size,
                              hipStream_t stream) {
    const float* x    = (const float*)d_in[0];
    const int*   ei   = (const int*)d_in[1];
    const float* W1   = (const float*)d_in[2];
    const float* b1   = (const float*)d_in[3];
    const float* W2   = (const float*)d_in[4];
    const float* b2   = (const float*)d_in[5];
    const float* linW = (const float*)d_in[6];
    const float* linb = (const float*)d_in[7];

    int n = in_sizes[0] / D128;
    int E = in_sizes[1] / 2;
    const int* src = ei;
    const int* dst = ei + E;

    float* out = (float*)d_out;
    float* ws  = (float*)d_ws;

    // ws (floats): csr[2E] | indeg[n] | dinv[n] | row_ptr[n+1] | bsum[256]
    //              | cursor[n] | align | x1[n*128] | x2[n*128] | h[n*64 uints]
    size_t o = 0;
    float2* csr   = (float2*)(ws + o);  o += 2 * (size_t)E;
    int*   indeg  = (int*)(ws + o);     o += n;
    float* dinv   = ws + o;             o += n;
    int*   row_ptr= (int*)(ws + o);     o += n + 1;
    int*   bsum   = (int*)(ws + o);     o += 256;
    int*   cursor = (int*)(ws + o);     o += n;
    o = (o + 3) & ~(size_t)3;
    float* x1     = ws + o;             o += (size_t)n * D128;
    float* x2     = ws + o;             o += (size_t)n * D128;
    float* h      = ws + o;             // bf16-packed, n*64 uints

    int gn = (n + 255) / 256;
    int gE  = (E + 255) / 256;          // fill: 1 edge/thread (R12 proven)
    int gE4 = (E + 1023) / 1024;        // count: 4 edges/thread
    int gemmBlocks = (n + 63) / 64;
    int aggBlocks  = (n + 3) / 4;

    // CSR prep
    (void)hipMemsetAsync(indeg, 0, (size_t)n * sizeof(int), stream);
    k_count<<<gE4, 256, 0, stream>>>(dst, indeg, E);
    k_scan1<<<gn, 256, 0, stream>>>(indeg, row_ptr, bsum, dinv, n);
    k_scan2<<<1, 256, 0, stream>>>(bsum, gn);
    k_scan3<<<gn, 256, 0, stream>>>(row_ptr, bsum, cursor, n, E);

    // gemm1 (h = bf16(x@W1)) fused with CSR fill
    k_gemm1_fill<<<gemmBlocks + gE, 256, 0, stream>>>(
        x, W1, h, n, src, dst, dinv, cursor, csr, E, gemmBlocks);

    // layer 1 aggregate
    k_agg_csr<<<aggBlocks, 256, 0, stream>>>((const unsigned int*)h, row_ptr, csr, dinv, b1, x1, n);

    // layer 2 gemm + first half of final linear (shared A staging)
    k_gemm_dual<<<gemmBlocks, 256, 0, stream>>>(x1, W2, linW, h, out, n);

    // layer 2 aggregate
    k_agg_csr<<<aggBlocks, 256, 0, stream>>>((const unsigned int*)h, row_ptr, csr, dinv, b2, x2, n);

    // final: out += x2 @ linW[128:256] + linb
    k_gemm_mfma<<<gemmBlocks, 256, 0, stream>>>(x2, linW + 128 * D128, linb, out, n, 0, 1);
}

// Round 15
// 232.072 us; speedup vs baseline: 1.0460x; 1.0137x over previous
//
#include <hip/hip_runtime.h>

// GCN: x1 = relu(Agg(x@W1)+b1); x2 = relu(Agg(x1@W2)+b2); out = [x1,x2]@linW + linb
// Agg via CSR (counting sort) + per-node wave gather-reduce; h stored bf16.
// R15 = R12 base (228.5us, best) with GEMMs in plain bf16 MFMA (1 mfma/tile):
// harness threshold 1.5e-2 = 8x bf16-eps is calibrated for bf16 compute, so
// the bf16x3 emulation (3 mfma/tile) was over-precision. Halves GEMM LDS
// (more fill blocks co-resident in the fused dispatch) and cuts MFMA work 3x.

#define D128 128

typedef __attribute__((ext_vector_type(8))) short bf16x8;
typedef __attribute__((ext_vector_type(4))) float f32x4;

__device__ __forceinline__ unsigned short f2bf_bits(float v) {
    unsigned int u = __float_as_uint(v);
    unsigned int r = u + 0x7FFFu + ((u >> 16) & 1u);   // RNE
    return (unsigned short)(r >> 16);
}

// ---------- degree count: 4 edges/thread ----------
__global__ void k_count(const int* __restrict__ dst, int* __restrict__ indeg, int E) {
    int base = (blockIdx.x * 256 + threadIdx.x) * 4;
    if (base + 3 < E) {
        int4 d = *(const int4*)&dst[base];
        atomicAdd(&indeg[d.x], 1);
        atomicAdd(&indeg[d.y], 1);
        atomicAdd(&indeg[d.z], 1);
        atomicAdd(&indeg[d.w], 1);
    } else {
        for (int e = base; e < E; ++e) atomicAdd(&indeg[dst[e]], 1);
    }
}

// ---------- scan (exclusive) over indeg -> row_ptr ; fused dinv ----------
__global__ void k_scan1(const int* __restrict__ indeg, int* __restrict__ row_ptr,
                        int* __restrict__ bsum, float* __restrict__ dinv, int n) {
    __shared__ int tmp[256];
    int i = blockIdx.x * 256 + threadIdx.x;
    int v = (i < n) ? indeg[i] : 0;
    if (i < n) dinv[i] = rsqrtf((float)(v + 1));  // +1 self loop
    tmp[threadIdx.x] = v;
    __syncthreads();
    for (int off = 1; off < 256; off <<= 1) {
        int t = (threadIdx.x >= off) ? tmp[threadIdx.x - off] : 0;
        __syncthreads();
        tmp[threadIdx.x] += t;
        __syncthreads();
    }
    if (i < n) row_ptr[i] = tmp[threadIdx.x] - v;
    if (threadIdx.x == 255) bsum[blockIdx.x] = tmp[255];
}

__global__ void k_scan2(int* __restrict__ bsum, int nb) {  // one block, nb<=256
    __shared__ int tmp[256];
    int v = (threadIdx.x < nb) ? bsum[threadIdx.x] : 0;
    tmp[threadIdx.x] = v;
    __syncthreads();
    for (int off = 1; off < 256; off <<= 1) {
        int t = (threadIdx.x >= off) ? tmp[threadIdx.x - off] : 0;
        __syncthreads();
        tmp[threadIdx.x] += t;
        __syncthreads();
    }
    if (threadIdx.x < nb) bsum[threadIdx.x] = tmp[threadIdx.x] - v;
}

__global__ void k_scan3(int* __restrict__ row_ptr, const int* __restrict__ bsum,
                        int* __restrict__ cursor, int n, int E) {
    int i = blockIdx.x * 256 + threadIdx.x;
    if (i < n) {
        int r = row_ptr[i] + bsum[blockIdx.x];
        row_ptr[i] = r;
        cursor[i] = r;
    }
    if (blockIdx.x == 0 && threadIdx.x == 0) row_ptr[n] = E;
}

// ---------- fused aggregate + bias + relu ; h is packed bf16x2 (R12 proven) ----------
__global__ __launch_bounds__(256) void k_agg_csr(
    const unsigned int* __restrict__ h, const int* __restrict__ row_ptr,
    const float2* __restrict__ csr, const float* __restrict__ dinv,
    const float* __restrict__ bias, float* __restrict__ o, int n)
{
    int node = blockIdx.x * 4 + (threadIdx.x >> 6);
    int lane = threadIdx.x & 63;
    if (node >= n) return;
    float dv = dinv[node];
    unsigned int su = h[node * 64 + lane];
    float ax = dv * dv * __uint_as_float(su << 16);
    float ay = dv * dv * __uint_as_float(su & 0xFFFF0000u);
    int j = row_ptr[node], end = row_ptr[node + 1];
    for (; j + 7 < end; j += 8) {
        float2 c0 = csr[j+0], c1 = csr[j+1], c2 = csr[j+2], c3 = csr[j+3];
        float2 c4 = csr[j+4], c5 = csr[j+5], c6 = csr[j+6], c7 = csr[j+7];
        unsigned int u0 = h[__float_as_int(c0.x) * 64 + lane];
        unsigned int u1 = h[__float_as_int(c1.x) * 64 + lane];
        unsigned int u2 = h[__float_as_int(c2.x) * 64 + lane];
        unsigned int u3 = h[__float_as_int(c3.x) * 64 + lane];
        unsigned int u4 = h[__float_as_int(c4.x) * 64 + lane];
        unsigned int u5 = h[__float_as_int(c5.x) * 64 + lane];
        unsigned int u6 = h[__float_as_int(c6.x) * 64 + lane];
        unsigned int u7 = h[__float_as_int(c7.x) * 64 + lane];
        ax += c0.y*__uint_as_float(u0 << 16) + c1.y*__uint_as_float(u1 << 16)
            + c2.y*__uint_as_float(u2 << 16) + c3.y*__uint_as_float(u3 << 16)
            + c4.y*__uint_as_float(u4 << 16) + c5.y*__uint_as_float(u5 << 16)
            + c6.y*__uint_as_float(u6 << 16) + c7.y*__uint_as_float(u7 << 16);
        ay += c0.y*__uint_as_float(u0 & 0xFFFF0000u) + c1.y*__uint_as_float(u1 & 0xFFFF0000u)
            + c2.y*__uint_as_float(u2 & 0xFFFF0000u) + c3.y*__uint_as_float(u3 & 0xFFFF0000u)
            + c4.y*__uint_as_float(u4 & 0xFFFF0000u) + c5.y*__uint_as_float(u5 & 0xFFFF0000u)
            + c6.y*__uint_as_float(u6 & 0xFFFF0000u) + c7.y*__uint_as_float(u7 & 0xFFFF0000u);
    }
    for (; j + 3 < end; j += 4) {
        float2 c0 = csr[j+0], c1 = csr[j+1], c2 = csr[j+2], c3 = csr[j+3];
        unsigned int u0 = h[__float_as_int(c0.x) * 64 + lane];
        unsigned int u1 = h[__float_as_int(c1.x) * 64 + lane];
        unsigned int u2 = h[__float_as_int(c2.x) * 64 + lane];
        unsigned int u3 = h[__float_as_int(c3.x) * 64 + lane];
        ax += c0.y*__uint_as_float(u0 << 16) + c1.y*__uint_as_float(u1 << 16)
            + c2.y*__uint_as_float(u2 << 16) + c3.y*__uint_as_float(u3 << 16);
        ay += c0.y*__uint_as_float(u0 & 0xFFFF0000u) + c1.y*__uint_as_float(u1 & 0xFFFF0000u)
            + c2.y*__uint_as_float(u2 & 0xFFFF0000u) + c3.y*__uint_as_float(u3 & 0xFFFF0000u);
    }
    for (; j < end; ++j) {
        float2 c = csr[j];
        unsigned int u = h[__float_as_int(c.x) * 64 + lane];
        ax += c.y * __uint_as_float(u << 16);
        ay += c.y * __uint_as_float(u & 0xFFFF0000u);
    }
    float2 bv = ((const float2*)bias)[lane];
    float2 ov = {fmaxf(ax + bv.x, 0.f), fmaxf(ay + bv.y, 0.f)};
    ((float2*)o)[node * 64 + lane] = ov;
}

// ---------- MFMA GEMM building blocks (plain bf16, layouts R10-verified) ----------
__device__ __forceinline__ void stage_A_tile(
    const float* __restrict__ A, int brow, int n, int tid,
    unsigned short* __restrict__ Ah)
{
    const float4* A4 = (const float4*)(A + (size_t)brow * D128);
#pragma unroll
    for (int it = 0; it < 8; ++it) {
        int f = it * 256 + tid;
        int r = f >> 5, k4 = f & 31;
        float4 v = make_float4(0.f, 0.f, 0.f, 0.f);
        if (brow + r < n) v = A4[f];
        int lane_ = (r & 15) + 16 * ((k4 >> 1) & 3);
        int base = ((((k4 >> 3) * 4 + (r >> 4)) * 64 + lane_) << 3) + (k4 & 1) * 4;
        ushort4 hh;
        unsigned short* hp = (unsigned short*)&hh;
        hp[0] = f2bf_bits(v.x); hp[1] = f2bf_bits(v.y);
        hp[2] = f2bf_bits(v.z); hp[3] = f2bf_bits(v.w);
        *(ushort4*)&Ah[base] = hh;
    }
}

__device__ __forceinline__ void load_W_s(
    const float* __restrict__ W, int s, int colbase, int lanen, int kb,
    bf16x8 wh[2])
{
#pragma unroll
    for (int t = 0; t < 2; ++t)
#pragma unroll
        for (int j = 0; j < 8; ++j)
            wh[t][j] = (short)f2bf_bits(W[(size_t)(s * 32 + kb + j) * D128 + colbase + t * 16 + lanen]);
}

__device__ __forceinline__ void epilogue(
    f32x4 acc[4][2], float* __restrict__ C, const float* __restrict__ bias,
    int brow, int n, int colbase, int lanen, int l, int out_bf, int addC)
{
    float bv[2] = {0.f, 0.f};
    if (bias) { bv[0] = bias[colbase + lanen]; bv[1] = bias[colbase + 16 + lanen]; }
    int rsub = (l >> 4) * 4;
    if (out_bf) {
        unsigned short* Cb = (unsigned short*)C;
#pragma unroll
        for (int m = 0; m < 4; ++m)
#pragma unroll
            for (int t = 0; t < 2; ++t)
#pragma unroll
                for (int r = 0; r < 4; ++r) {
                    int row = brow + m * 16 + rsub + r;
                    if (row < n)
                        Cb[(size_t)row * D128 + colbase + t * 16 + lanen] = f2bf_bits(acc[m][t][r]);
                }
    } else {
#pragma unroll
        for (int m = 0; m < 4; ++m)
#pragma unroll
            for (int t = 0; t < 2; ++t)
#pragma unroll
                for (int r = 0; r < 4; ++r) {
                    int row = brow + m * 16 + rsub + r;
                    if (row < n) {
                        size_t idx = (size_t)row * D128 + colbase + t * 16 + lanen;
                        float v = acc[m][t][r] + bv[t];
                        if (addC) v += C[idx];
                        C[idx] = v;
                    }
                }
    }
}

__device__ __forceinline__ void gemm_core(
    const float* __restrict__ A, const float* __restrict__ W,
    const float* __restrict__ bias, float* __restrict__ C,
    int n, int out_bf, int addC, int bid, int tid,
    unsigned short* __restrict__ Ah)
{
    int l = tid & 63;
    int wv = tid >> 6;
    int brow = bid * 64;
    int colbase = wv * 32;
    int lanen = l & 15;
    int kb = (l >> 4) * 8;

    f32x4 acc[4][2];
#pragma unroll
    for (int m = 0; m < 4; ++m)
#pragma unroll
        for (int t = 0; t < 2; ++t) acc[m][t] = (f32x4){0.f, 0.f, 0.f, 0.f};

    stage_A_tile(A, brow, n, tid, Ah);
    __syncthreads();

#pragma unroll
    for (int s = 0; s < 4; ++s) {
        bf16x8 wh[2];
        load_W_s(W, s, colbase, lanen, kb, wh);
#pragma unroll
        for (int m = 0; m < 4; ++m) {
            bf16x8 ah = *(const bf16x8*)&Ah[((s * 4 + m) * 64 + l) * 8];
#pragma unroll
            for (int t = 0; t < 2; ++t)
                acc[m][t] = __builtin_amdgcn_mfma_f32_16x16x32_bf16(ah, wh[t], acc[m][t], 0, 0, 0);
        }
    }
    epilogue(acc, C, bias, brow, n, colbase, lanen, l, out_bf, addC);
}

// ---------- fused: gemm1 (blocks < gemmBlocks) + CSR fill (rest) ----------
__global__ __launch_bounds__(256, 2) void k_gemm1_fill(
    const float* __restrict__ x, const float* __restrict__ W1,
    float* __restrict__ h, int n,
    const int* __restrict__ src, const int* __restrict__ dst,
    const float* __restrict__ dinv, int* __restrict__ cursor,
    float2* __restrict__ csr, int E, int gemmBlocks)
{
    __shared__ unsigned short Ah[4 * 4 * 64 * 8];   // 16 KB
    if (blockIdx.x < gemmBlocks) {
        gemm_core(x, W1, nullptr, h, n, 1, 0, blockIdx.x, threadIdx.x, Ah);
    } else {
        int e = (blockIdx.x - gemmBlocks) * 256 + threadIdx.x;
        if (e >= E) return;
        int s = src[e], d = dst[e];
        int pos = atomicAdd(&cursor[d], 1);
        csr[pos] = make_float2(__int_as_float(s), dinv[s] * dinv[d]);
    }
}

// ---------- standalone single-source gemm (gemm3b) ----------
__global__ __launch_bounds__(256, 2) void k_gemm_mfma(
    const float* __restrict__ A, const float* __restrict__ W,
    const float* __restrict__ bias, float* __restrict__ C,
    int n, int out_bf, int addC)
{
    __shared__ unsigned short Ah[4 * 4 * 64 * 8];
    gemm_core(A, W, bias, C, n, out_bf, addC, blockIdx.x, threadIdx.x, Ah);
}

// ---------- dual: h2 = bf16(x1@W2), p = x1@linW_top (one A staging) ----------
__global__ __launch_bounds__(256, 2) void k_gemm_dual(
    const float* __restrict__ A, const float* __restrict__ W2,
    const float* __restrict__ Wtop, float* __restrict__ hOut,
    float* __restrict__ pOut, int n)
{
    __shared__ unsigned short Ah[4 * 4 * 64 * 8];
    int tid = threadIdx.x;
    int l = tid & 63;
    int wv = tid >> 6;
    int brow = blockIdx.x * 64;
    int colbase = wv * 32;
    int lanen = l & 15;
    int kb = (l >> 4) * 8;

    f32x4 accA[4][2], accB[4][2];
#pragma unroll
    for (int m = 0; m < 4; ++m)
#pragma unroll
        for (int t = 0; t < 2; ++t) {
            accA[m][t] = (f32x4){0.f, 0.f, 0.f, 0.f};
            accB[m][t] = (f32x4){0.f, 0.f, 0.f, 0.f};
        }

    stage_A_tile(A, brow, n, tid, Ah);
    __syncthreads();

#pragma unroll
    for (int s = 0; s < 4; ++s) {
        bf16x8 whA[2], whB[2];
        load_W_s(W2, s, colbase, lanen, kb, whA);
        load_W_s(Wtop, s, colbase, lanen, kb, whB);
#pragma unroll
        for (int m = 0; m < 4; ++m) {
            bf16x8 ah = *(const bf16x8*)&Ah[((s * 4 + m) * 64 + l) * 8];
#pragma unroll
            for (int t = 0; t < 2; ++t) {
                accA[m][t] = __builtin_amdgcn_mfma_f32_16x16x32_bf16(ah, whA[t], accA[m][t], 0, 0, 0);
                accB[m][t] = __builtin_amdgcn_mfma_f32_16x16x32_bf16(ah, whB[t], accB[m][t], 0, 0, 0);
            }
        }
    }
    epilogue(accA, hOut, nullptr, brow, n, colbase, lanen, l, 1, 0);
    epilogue(accB, pOut, nullptr, brow, n, colbase, lanen, l, 0, 0);
}

extern "C" void kernel_launch(void* const* d_in, const int* in_sizes, int n_in,
                              void* d_out, int out_size, void* d_ws, size_t ws_size,
                              hipStream_t stream) {
    const float* x    = (const float*)d_in[0];
    const int*   ei   = (const int*)d_in[1];
    const float* W1   = (const float*)d_in[2];
    const float* b1   = (const float*)d_in[3];
    const float* W2   = (const float*)d_in[4];
    const float* b2   = (const float*)d_in[5];
    const float* linW = (const float*)d_in[6];
    const float* linb = (const float*)d_in[7];

    int n = in_sizes[0] / D128;
    int E = in_sizes[1] / 2;
    const int* src = ei;
    const int* dst = ei + E;

    float* out = (float*)d_out;
    float* ws  = (float*)d_ws;

    // ws (floats): csr[2E] | indeg[n] | dinv[n] | row_ptr[n+1] | bsum[256]
    //              | cursor[n] | align | x1[n*128] | x2[n*128] | h[n*64 uints]
    size_t o = 0;
    float2* csr   = (float2*)(ws + o);  o += 2 * (size_t)E;
    int*   indeg  = (int*)(ws + o);     o += n;
    float* dinv   = ws + o;             o += n;
    int*   row_ptr= (int*)(ws + o);     o += n + 1;
    int*   bsum   = (int*)(ws + o);     o += 256;
    int*   cursor = (int*)(ws + o);     o += n;
    o = (o + 3) & ~(size_t)3;
    float* x1     = ws + o;             o += (size_t)n * D128;
    float* x2     = ws + o;             o += (size_t)n * D128;
    float* h      = ws + o;             // bf16-packed, n*64 uints

    int gn = (n + 255) / 256;
    int gE  = (E + 255) / 256;          // fill: 1 edge/thread
    int gE4 = (E + 1023) / 1024;        // count: 4 edges/thread
    int gemmBlocks = (n + 63) / 64;
    int aggBlocks  = (n + 3) / 4;

    // CSR prep
    (void)hipMemsetAsync(indeg, 0, (size_t)n * sizeof(int), stream);
    k_count<<<gE4, 256, 0, stream>>>(dst, indeg, E);
    k_scan1<<<gn, 256, 0, stream>>>(indeg, row_ptr, bsum, dinv, n);
    k_scan2<<<1, 256, 0, stream>>>(bsum, gn);
    k_scan3<<<gn, 256, 0, stream>>>(row_ptr, bsum, cursor, n, E);

    // gemm1 (h = bf16(x@W1)) fused with CSR fill
    k_gemm1_fill<<<gemmBlocks + gE, 256, 0, stream>>>(
        x, W1, h, n, src, dst, dinv, cursor, csr, E, gemmBlocks);

    // layer 1 aggregate
    k_agg_csr<<<aggBlocks, 256, 0, stream>>>((const unsigned int*)h, row_ptr, csr, dinv, b1, x1, n);

    // layer 2 gemm + first half of final linear (shared A staging)
    k_gemm_dual<<<gemmBlocks, 256, 0, stream>>>(x1, W2, linW, h, out, n);

    // layer 2 aggregate
    k_agg_csr<<<aggBlocks, 256, 0, stream>>>((const unsigned int*)h, row_ptr, csr, dinv, b2, x2, n);

    // final: out += x2 @ linW[128:256] + linb
    k_gemm_mfma<<<gemmBlocks, 256, 0, stream>>>(x2, linW + 128 * D128, linb, out, n, 0, 1);
}